// Round 4
// baseline (13.963 us; speedup 1.0000x reference)
//
#include <hip/hip_runtime.h>

constexpr int C    = 512;
constexpr int HALF = 50;
constexpr int W    = 2 * HALF + 1;   // 101
constexpr int WAVES = 4;             // waves (= bt rows) per block

// One 64-lane wave per (b,t) row, NO LDS. Timestamps are uniform in [0,1e5)
// with a +-50 window, so ~99.9% of gather indices clip to 0 or 100: compute
// exp(row[0]) / exp(row[100]) once per wave (scalar path), handle interior
// indices (expected ~0.5 per 512-wide row) with a rare predicated global
// gather. Contiguous int4 loads / float4 stores; one shfl_xor butterfly.
__global__ __launch_bounds__(256, 8) void TimeAttention_33715493274067_kernel(
    const int*   __restrict__ concepts,   // [B,T]
    const int*   __restrict__ tgt_ts,     // [B,T]
    const int*   __restrict__ ctx_ts,     // [B,C]
    const int*   __restrict__ mask,       // [B,C]
    const float* __restrict__ emb,        // [V,W]
    const float* __restrict__ bias,       // [W]
    float*       __restrict__ out)        // [B,T,C]
{
    const int tid  = threadIdx.x;
    const int lane = tid & 63;
    // bt is uniform per wave; force it scalar so concept/tt/row-end loads
    // become s_loads and the whole per-row setup lives in the scalar unit.
    const int bt = __builtin_amdgcn_readfirstlane(blockIdx.x * WAVES + (tid >> 6));
    const int b  = bt >> 9;               // T == 512

    // Per-lane context loads: two contiguous 4-wide chunks -> each vector
    // memop covers a contiguous 1KB segment.
    const int cbase0 = b * C + lane * 4;
    const int cbase1 = cbase0 + 256;
    const int4 ct0 = *(const int4*)(ctx_ts + cbase0);
    const int4 ct1 = *(const int4*)(ctx_ts + cbase1);
    const int4 mk0 = *(const int4*)(mask   + cbase0);
    const int4 mk1 = *(const int4*)(mask   + cbase1);

    const int concept = concepts[bt];     // scalar load (bt uniform)
    const int tt      = tgt_ts[bt];

    const float* erow = emb + (size_t)concept * W;
    // The two clip values: computed once per wave.
    const float eLo = __expf(erow[0]       + bias[0]);
    const float eHi = __expf(erow[W - 1]   + bias[W - 1]);

    const int d[8]  = {ct0.x, ct0.y, ct0.z, ct0.w, ct1.x, ct1.y, ct1.z, ct1.w};
    const int mm[8] = {mk0.x, mk0.y, mk0.z, mk0.w, mk1.x, mk1.y, mk1.z, mk1.w};

    float e[8];
    float s = 0.0f;
    #pragma unroll
    for (int i = 0; i < 8; ++i) {
        const int idx = min(max(d[i] - tt, -HALF), HALF) + HALF;  // [0,100]
        float v;
        if (__builtin_expect((unsigned)(idx - 1) < 99u, 0)) {
            // Rare interior hit (~0.1% of elements): direct gather.
            v = __expf(erow[idx] + bias[idx]);
        } else {
            v = idx ? eHi : eLo;
        }
        e[i] = mm[i] ? 0.0f : v;          // masked -> exactly 0 (exp(-1e9))
        s += e[i];
    }

    // Wave-wide sum (butterfly) -> every lane holds the row sum.
    #pragma unroll
    for (int o = 1; o < 64; o <<= 1) s += __shfl_xor(s, o, 64);

    const float inv = __builtin_amdgcn_rcpf(s);

    float4 o0 = {e[0] * inv, e[1] * inv, e[2] * inv, e[3] * inv};
    float4 o1 = {e[4] * inv, e[5] * inv, e[6] * inv, e[7] * inv};
    float* obase = out + (size_t)bt * C;
    *(float4*)(obase + lane * 4)       = o0;   // contiguous 1KB per instr
    *(float4*)(obase + 256 + lane * 4) = o1;
}

extern "C" void kernel_launch(void* const* d_in, const int* in_sizes, int n_in,
                              void* d_out, int out_size, void* d_ws, size_t ws_size,
                              hipStream_t stream) {
    const int*   concepts = (const int*)  d_in[0];
    const int*   tgt_ts   = (const int*)  d_in[1];
    const int*   ctx_ts   = (const int*)  d_in[2];
    const int*   mask     = (const int*)  d_in[3];
    const float* emb      = (const float*)d_in[4];
    const float* bias     = (const float*)d_in[5];
    float*       out      = (float*)      d_out;

    const int n_bt = in_sizes[0];               // B*T = 16384
    const int grid = n_bt / WAVES;              // 4096 blocks
    TimeAttention_33715493274067_kernel<<<grid, 256, 0, stream>>>(
        concepts, tgt_ts, ctx_ts, mask, emb, bias, out);
}